// Round 14
// baseline (458.027 us; speedup 1.0000x reference)
//
#include <hip/hip_runtime.h>
#include <math.h>

#define BATCH_C 16384
#define SPW 2   // segments (batch rows) per wave; each wave does both sides + head

typedef float f32x4  __attribute__((ext_vector_type(4)));
typedef f32x4 __attribute__((aligned(4))) f32x4_u;   // dword-aligned vector load
typedef float f32x16 __attribute__((ext_vector_type(16)));
typedef short s16x8  __attribute__((ext_vector_type(8)));

typedef union { unsigned u[4]; s16x8 v; } abfrag_t;

// branchless RNE fp32->bf16 (no NaN inputs here), result in LOW 16 bits
static __device__ inline unsigned rlo_f(float x) {
    unsigned u = __float_as_uint(x);
    return (u + 0x7fffu + ((u >> 16) & 1u)) >> 16;
}
// same, result pre-positioned in HIGH 16 bits
static __device__ inline unsigned rhi_f(float x) {
    unsigned u = __float_as_uint(x);
    return (u + 0x7fffu + ((u >> 16) & 1u)) & 0xffff0000u;
}

// ---------------------------------------------------------------------------
// Kernel 1: segment boundary detection for BOTH sides (grid.y = side).
// ---------------------------------------------------------------------------
__global__ __launch_bounds__(256) void seg_starts_kernel(
    const int* __restrict__ lseg, const int* __restrict__ rseg, int n,
    int* __restrict__ lstart, int* __restrict__ rstart)
{
    const int* __restrict__ seg = blockIdx.y ? rseg : lseg;
    int* __restrict__ start = blockIdx.y ? rstart : lstart;
    int i = blockIdx.x * blockDim.x + threadIdx.x;
    if (i >= n) return;
    int s = seg[i];
    int prev = (i == 0) ? -1 : seg[i - 1];
    for (int b = prev + 1; b <= s; ++b) start[b] = i;
    if (i == n - 1) {
        for (int b = s + 1; b <= BATCH_C; ++b) start[b] = n;
    }
}

// ---------------------------------------------------------------------------
// Kernel 2 (FUSED, TEMPLATED FOR ABLATION): MODE=0 is byte-equivalent to the
// R12 37.3us kernel (plus a reps loop). Ablation bits (work goes to scratch):
//   MODE&1: skip CONV  (opaque const fragments; FETCH kept live via asm)
//   MODE&2: skip in-loop FETCH (stale regs, asm-perturbed to defeat hoisting)
//   MODE&4: skip MFMA+EPI (CONV+FETCH+control floor; CONV kept live via asm)
//   MODE&8: skip EPI   (acc += c[0] keeps MFMA live)
// Keep-alive asm per rule #17; opaque perturbation defeats loop-invariant
// hoisting of the remaining stages.
// ---------------------------------------------------------------------------
template<int MODE>
__global__ __launch_bounds__(256, 2) void fused_kernel(
    const float* __restrict__ lfeats, const float* __restrict__ rfeats,
    const int* __restrict__ lstart, const int* __restrict__ rstart,
    const float* __restrict__ W1, const float* __restrict__ b1,
    const float* __restrict__ Wc1, const float* __restrict__ bc1,
    const float* __restrict__ Wc2, const float* __restrict__ bc2,
    float* __restrict__ out, int nunits, int reps)
{
    const int lane = threadIdx.x & 63;
    const int wv   = threadIdx.x >> 6;
    const int S0   = (blockIdx.x * 4 + wv) * SPW;
    const int r    = lane & 31;
    const int hh   = lane >> 5;
    const int nmax = nunits - 1;
    const int ofs1 = hh ? 5 : 4;

    __shared__ __align__(16) short sBh[2][32][16];
    __shared__ __align__(16) short sBl[2][32][16];
    __shared__ __align__(16) float rowbuf[4][SPW][128];

    {
        const int t    = threadIdx.x;
        const int tile = t >> 7;
        const int col  = (t >> 2) & 31;
        const int k0   = (t & 3) * 4;
        const int ch   = tile * 32 + col;
#pragma unroll
        for (int q = 0; q < 4; ++q) {
            const int k = k0 + q;
            float v = 0.0f;
            if (k < 9) v = W1[k * 64 + ch];
            else if (k == 9) v = b1[ch];
            unsigned hi = rlo_f(v);
            float d = v - __uint_as_float(hi << 16);
            sBh[tile][col][k] = (short)hi;
            sBl[tile][col][k] = (short)rlo_f(d);
        }
    }
    __syncthreads();

    const s16x8 bh0 = *reinterpret_cast<const s16x8*>(&sBh[0][r][hh * 8]);
    const s16x8 bh1 = *reinterpret_cast<const s16x8*>(&sBh[1][r][hh * 8]);
    const s16x8 bl0 = *reinterpret_cast<const s16x8*>(&sBl[0][r][hh * 8]);
    const s16x8 bl1 = *reinterpret_cast<const s16x8*>(&sBl[1][r][hh * 8]);
    const f32x16 kZ = (f32x16)0.0f;

    // opaque values for ablation stubs (compiler cannot constant-fold)
    unsigned opq = lane * 2654435761u + 12345u;
    asm volatile("" : "+v"(opq));
    const float opqv = __uint_as_float((opq & 0x007fffffu) | 0x3e000000u);
    f32x16 opqf;
#pragma unroll
    for (int i = 0; i < 16; ++i) opqf[i] = opqv;

    rowbuf[wv][0][lane] = 0.0f;  rowbuf[wv][0][64 + lane] = 0.0f;
    rowbuf[wv][1][lane] = 0.0f;  rowbuf[wv][1][64 + lane] = 0.0f;

    const int bidx = S0 + (lane <= SPW ? lane : SPW);
    const int svl = lstart[bidx];
    const int svr = rstart[bidx];
    const int sLv = __shfl(svl, 0, 64);
    const int e1L = __shfl(svl, 1, 64);
    const int e2L = __shfl(svl, 2, 64);
    const int sRv = __shfl(svr, 0, 64);
    const int e1R = __shfl(svr, 1, 64);
    const int e2R = __shfl(svr, 2, 64);
    const int endL = e2L, endR = e2R;

#define FETCH_(F, POS, Q0,Q1,Q2,Q3,Q4,Q5,Q6,Q7) do {                      \
        int u_ = (POS) + r; if (u_ > nmax) u_ = nmax;                     \
        const float* fp_ = (F) + (size_t)u_ * 9;                          \
        f32x4 x0_ = *reinterpret_cast<const f32x4_u*>(fp_);               \
        f32x4 x1_ = *reinterpret_cast<const f32x4_u*>(fp_ + ofs1);        \
        Q0 = hh ? x1_.w : x0_.x;                                          \
        Q1 = x0_.y; Q2 = x0_.z; Q3 = x0_.w;                               \
        Q4 = x1_.x; Q5 = x1_.y; Q6 = x1_.z; Q7 = x1_.w;                   \
    } while (0)

#define CONV_(Q0,Q1,Q2,Q3,Q4,Q5,Q6,Q7, CNT, AH, AL) do {                  \
    unsigned u0_=__float_as_uint(Q0), u1_=__float_as_uint(Q1),            \
             u2_=__float_as_uint(Q2), u3_=__float_as_uint(Q3),            \
             u4_=__float_as_uint(Q4), u5_=__float_as_uint(Q5),            \
             u6_=__float_as_uint(Q6), u7_=__float_as_uint(Q7);            \
    float d0_=Q0-__uint_as_float(u0_&0xffff0000u);                        \
    float d1_=Q1-__uint_as_float(u1_&0xffff0000u);                        \
    float d2_=Q2-__uint_as_float(u2_&0xffff0000u);                        \
    float d3_=Q3-__uint_as_float(u3_&0xffff0000u);                        \
    float d4_=Q4-__uint_as_float(u4_&0xffff0000u);                        \
    float d5_=Q5-__uint_as_float(u5_&0xffff0000u);                        \
    float d6_=Q6-__uint_as_float(u6_&0xffff0000u);                        \
    float d7_=Q7-__uint_as_float(u7_&0xffff0000u);                        \
    unsigned h01_=(u0_>>16)|(hh?0x3F800000u:(u1_&0xffff0000u));           \
    unsigned l01_=rlo_f(d0_)|(hh?0u:rhi_f(d1_));                          \
    unsigned h23_=(u2_>>16)|(u3_&0xffff0000u);                            \
    unsigned h45_=(u4_>>16)|(u5_&0xffff0000u);                            \
    unsigned h67_=(u6_>>16)|(u7_&0xffff0000u);                            \
    unsigned l23_=rlo_f(d2_)|rhi_f(d3_);                                  \
    unsigned l45_=rlo_f(d4_)|rhi_f(d5_);                                  \
    unsigned l67_=rlo_f(d6_)|rhi_f(d7_);                                  \
    const bool v_ = (r < (CNT));                                          \
    const bool k_ = v_ && (hh == 0);                                      \
    AH.u[0]=v_?h01_:0u; AL.u[0]=v_?l01_:0u;                               \
    AH.u[1]=k_?h23_:0u; AL.u[1]=k_?l23_:0u;                               \
    AH.u[2]=k_?h45_:0u; AL.u[2]=k_?l45_:0u;                               \
    AH.u[3]=k_?h67_:0u; AL.u[3]=k_?l67_:0u;                               \
} while (0)

#define MFMAC_(AH, AL, C0, C1) do {                                       \
    C0 = __builtin_amdgcn_mfma_f32_32x32x16_bf16(AL.v, bh0, kZ, 0,0,0);   \
    C0 = __builtin_amdgcn_mfma_f32_32x32x16_bf16(AH.v, bl0, C0, 0,0,0);   \
    C0 = __builtin_amdgcn_mfma_f32_32x32x16_bf16(AH.v, bh0, C0, 0,0,0);   \
    C1 = __builtin_amdgcn_mfma_f32_32x32x16_bf16(AL.v, bh1, kZ, 0,0,0);   \
    C1 = __builtin_amdgcn_mfma_f32_32x32x16_bf16(AH.v, bl1, C1, 0,0,0);   \
    C1 = __builtin_amdgcn_mfma_f32_32x32x16_bf16(AH.v, bh1, C1, 0,0,0);   \
} while (0)

#define EPI_(C0, C1, A0, A1) do {                                         \
    float sA_=0.f,sB_=0.f,sC_=0.f,sD_=0.f,tA_=0.f,tB_=0.f,tC_=0.f,tD_=0.f;\
    _Pragma("unroll")                                                     \
    for (int t_=0; t_<4; ++t_) {                                          \
        sA_+=fmaxf(C0[t_],0.f);    sB_+=fmaxf(C0[t_+4],0.f);              \
        sC_+=fmaxf(C0[t_+8],0.f);  sD_+=fmaxf(C0[t_+12],0.f);             \
        tA_+=fmaxf(C1[t_],0.f);    tB_+=fmaxf(C1[t_+4],0.f);              \
        tC_+=fmaxf(C1[t_+8],0.f);  tD_+=fmaxf(C1[t_+12],0.f);             \
    }                                                                     \
    A0 += (sA_+sB_)+(sC_+sD_);                                            \
    A1 += (tA_+tB_)+(tC_+tD_);                                            \
} while (0)

#define STEP_(S) do {                                                     \
    int cnt_ = ec##S - base##S; if (cnt_ > 32) cnt_ = 32;                 \
    abfrag_t AH_, AL_;                                                    \
    if ((MODE & 1) == 0) {                                                \
        CONV_(p0##S,p1##S,p2##S,p3##S,p4##S,p5##S,p6##S,p7##S, cnt_, AH_, AL_);\
    } else {                                                              \
        AH_.u[0]=opq; AH_.u[1]=opq; AH_.u[2]=opq; AH_.u[3]=opq;           \
        AL_.u[0]=opq; AL_.u[1]=opq; AL_.u[2]=opq; AL_.u[3]=opq;           \
        asm volatile("" : "+v"(AH_.u[0]), "+v"(AL_.u[0]));                \
        asm volatile("" :: "v"(p0##S), "v"(p4##S));                       \
    }                                                                     \
    int nxt_ = base##S + cnt_;                                            \
    if ((MODE & 2) == 0) {                                                \
        int fpos_ = (nxt_ < end##S) ? nxt_ : 0;                           \
        FETCH_(f##S, fpos_, p0##S,p1##S,p2##S,p3##S,p4##S,p5##S,p6##S,p7##S);\
    } else {                                                              \
        asm volatile("" : "+v"(p0##S));                                   \
    }                                                                     \
    f32x16 c0_, c1_;                                                      \
    if ((MODE & 4) == 0) {                                                \
        MFMAC_(AH_, AL_, c0_, c1_);                                       \
    } else {                                                              \
        asm volatile("" :: "v"(AH_.u[0]),"v"(AH_.u[1]),"v"(AH_.u[2]),"v"(AH_.u[3]));\
        asm volatile("" :: "v"(AL_.u[0]),"v"(AL_.u[1]),"v"(AL_.u[2]),"v"(AL_.u[3]));\
        c0_ = opqf; c1_ = opqf;                                           \
    }                                                                     \
    if ((MODE & 12) == 0) {                                               \
        EPI_(c0_, c1_, ac0##S, ac1##S);                                   \
    } else if ((MODE & 4) != 0) {                                         \
        ac0##S += opqv; ac1##S += opqv;                                   \
    } else {                                                              \
        ac0##S += c0_[0]; ac1##S += c1_[0];                               \
        asm volatile("" :: "v"(c0_[8]), "v"(c1_[8]));                     \
    }                                                                     \
    base##S = nxt_;                                                       \
} while (0)

#define FLUSH_(S, SIDEOFS) do {                                           \
    if (base##S >= ec##S) {                                               \
        ac0##S += __shfl_xor(ac0##S, 32, 64);                             \
        ac1##S += __shfl_xor(ac1##S, 32, 64);                             \
        if (cs##S < SPW)                                                  \
            rowbuf[wv][cs##S][(SIDEOFS) + lane] = hh ? ac1##S : ac0##S;   \
        ac0##S = 0.0f; ac1##S = 0.0f;                                     \
        ++cs##S; ec##S = e2##S;                                           \
    }                                                                     \
} while (0)

    const float* __restrict__ fL = lfeats;
    const float* __restrict__ fR = rfeats;

    for (int rep = 0; rep < reps; ++rep) {
        asm volatile("" ::: "memory");   // force full recompute per rep

        int baseL = sLv, baseR = sRv;
        int csL, ecL, csR, ecR;
        if (baseL >= e1L) { csL = 1; ecL = e2L; } else { csL = 0; ecL = e1L; }
        if (baseR >= e1R) { csR = 1; ecR = e2R; } else { csR = 0; ecR = e1R; }
        float ac0L = 0.f, ac1L = 0.f, ac0R = 0.f, ac1R = 0.f;
        float p0L=0,p1L=0,p2L=0,p3L=0,p4L=0,p5L=0,p6L=0,p7L=0;
        float p0R=0,p1R=0,p2R=0,p3R=0,p4R=0,p5R=0,p6R=0,p7R=0;

        if (baseL < endL) FETCH_(fL, baseL, p0L,p1L,p2L,p3L,p4L,p5L,p6L,p7L);
        if (baseR < endR) FETCH_(fR, baseR, p0R,p1R,p2R,p3R,p4R,p5R,p6R,p7R);

        bool aL = baseL < endL, aR = baseR < endR;
        while (aL && aR) {
            STEP_(L);
            STEP_(R);
            FLUSH_(L, 0);
            FLUSH_(R, 64);
            aL = baseL < endL; aR = baseR < endR;
        }
        while (aL) { STEP_(L); FLUSH_(L, 0);  aL = baseL < endL; }
        while (aR) { STEP_(R); FLUSH_(R, 64); aR = baseR < endR; }
    }

#undef FLUSH_
#undef STEP_
#undef EPI_
#undef MFMAC_
#undef CONV_
#undef FETCH_

    asm volatile("s_waitcnt lgkmcnt(0)" ::: "memory");

    // ---- HEAD (as R12: coalesced Wc1 column reads) ----
    {
        const int j = lane & 31;
        const float* __restrict__ rb = &rowbuf[wv][hh][0];
        const float* __restrict__ wc = Wc1 + j;

        float accA = bc1[j], accB = 0.0f;
#pragma unroll 8
        for (int k = 0; k < 128; k += 4) {
            f32x4 v = *reinterpret_cast<const f32x4*>(rb + k);
            accA = fmaf(v.x, wc[(k + 0) * 32], accA);
            accB = fmaf(v.y, wc[(k + 1) * 32], accB);
            accA = fmaf(v.z, wc[(k + 2) * 32], accA);
            accB = fmaf(v.w, wc[(k + 3) * 32], accB);
        }
        float hsv = fmaxf(accA + accB, 0.0f) * Wc2[j];
#pragma unroll
        for (int off = 16; off > 0; off >>= 1) hsv += __shfl_xor(hsv, off, 64);

        if (j == 0) {
            float logit = hsv + bc2[0];
            out[S0 + hh] = 1.0f / (1.0f + expf(-logit));
        }
    }
}

// ---------------------------------------------------------------------------
extern "C" void kernel_launch(void* const* d_in, const int* in_sizes, int n_in,
                              void* d_out, int out_size, void* d_ws, size_t ws_size,
                              hipStream_t stream)
{
    const float* lfeats = (const float*)d_in[0];
    const float* rfeats = (const float*)d_in[1];
    const int*   lseg   = (const int*)d_in[2];
    const int*   rseg   = (const int*)d_in[3];
    const float* W1     = (const float*)d_in[4];
    const float* b1     = (const float*)d_in[5];
    const float* Wc1    = (const float*)d_in[6];
    const float* bc1    = (const float*)d_in[7];
    const float* Wc2    = (const float*)d_in[8];
    const float* bc2    = (const float*)d_in[9];
    float* out = (float*)d_out;

    const int n = in_sizes[2];  // N_UNITS per side

    int* lstart = (int*)d_ws;
    int* rstart = lstart + (BATCH_C + 16);

    // scratch output regions for ablation variants (ws is ~256MB)
    float* dump = (float*)((char*)d_ws + (1u << 20));
    const int REPS = 6;
    const int GRID = BATCH_C / (SPW * 4);

    seg_starts_kernel<<<dim3((n + 255) / 256, 2), 256, 0, stream>>>(
        lseg, rseg, n, lstart, rstart);

    // real pipeline (correct output)
    fused_kernel<0><<<GRID, 256, 0, stream>>>(
        lfeats, rfeats, lstart, rstart, W1, b1, Wc1, bc1, Wc2, bc2, out, n, 1);

    // ---- ablation probes (write to scratch; visible in rocprof top-5) ----
    fused_kernel<0><<<GRID, 256, 0, stream>>>(   // M0 baseline x6
        lfeats, rfeats, lstart, rstart, W1, b1, Wc1, bc1, Wc2, bc2,
        dump + 0 * 65536, n, REPS);
    fused_kernel<1><<<GRID, 256, 0, stream>>>(   // M1 no CONV
        lfeats, rfeats, lstart, rstart, W1, b1, Wc1, bc1, Wc2, bc2,
        dump + 1 * 65536, n, REPS);
    fused_kernel<2><<<GRID, 256, 0, stream>>>(   // M2 no in-loop FETCH
        lfeats, rfeats, lstart, rstart, W1, b1, Wc1, bc1, Wc2, bc2,
        dump + 2 * 65536, n, REPS);
    fused_kernel<4><<<GRID, 256, 0, stream>>>(   // M4 no MFMA+EPI
        lfeats, rfeats, lstart, rstart, W1, b1, Wc1, bc1, Wc2, bc2,
        dump + 3 * 65536, n, REPS);
    fused_kernel<8><<<GRID, 256, 0, stream>>>(   // M8 no EPI
        lfeats, rfeats, lstart, rstart, W1, b1, Wc1, bc1, Wc2, bc2,
        dump + 4 * 65536, n, REPS);
}

// Round 15
// 45.073 us; speedup vs baseline: 10.1618x; 10.1618x over previous
//
#include <hip/hip_runtime.h>
#include <math.h>

#define BATCH_C 16384

typedef float f32x4  __attribute__((ext_vector_type(4)));
typedef f32x4 __attribute__((aligned(4))) f32x4_u;   // dword-aligned vector load
typedef float f32x16 __attribute__((ext_vector_type(16)));
typedef short s16x8  __attribute__((ext_vector_type(8)));

typedef union { unsigned u[4]; s16x8 v; } abfrag_t;

// branchless RNE fp32->bf16 (no NaN inputs here), result in LOW 16 bits
static __device__ inline unsigned rlo_f(float x) {
    unsigned u = __float_as_uint(x);
    return (u + 0x7fffu + ((u >> 16) & 1u)) >> 16;
}
// same, result pre-positioned in HIGH 16 bits
static __device__ inline unsigned rhi_f(float x) {
    unsigned u = __float_as_uint(x);
    return (u + 0x7fffu + ((u >> 16) & 1u)) & 0xffff0000u;
}

// ---------------------------------------------------------------------------
// Kernel 1: segment boundary detection for BOTH sides (grid.y = side).
// ---------------------------------------------------------------------------
__global__ __launch_bounds__(256) void seg_starts_kernel(
    const int* __restrict__ lseg, const int* __restrict__ rseg, int n,
    int* __restrict__ lstart, int* __restrict__ rstart)
{
    const int* __restrict__ seg = blockIdx.y ? rseg : lseg;
    int* __restrict__ start = blockIdx.y ? rstart : lstart;
    int i = blockIdx.x * blockDim.x + threadIdx.x;
    if (i >= n) return;
    int s = seg[i];
    int prev = (i == 0) ? -1 : seg[i - 1];
    for (int b = prev + 1; b <= s; ++b) start[b] = i;
    if (i == n - 1) {
        for (int b = s + 1; b <= BATCH_C; ++b) start[b] = n;
    }
}

// ---------------------------------------------------------------------------
// Kernel 2 (FUSED, SPW=1): one batch row per wave (both sides + head).
// R14 ablation showed the R9 kernel is latency/control-bound, not
// instruction-bound: halve the per-wave serial chain and double the count
// of independent cold-load streams. Per wave: ~1 window/side avg, single
// unconditional flush (no cursor machinery), 1-row head split across
// half-waves. Pool machinery (dual-stream STEP, bf16 3-term split MFMA,
// dummy L2-resident prefetch) byte-identical to the 36.45us baseline.
// ---------------------------------------------------------------------------
__global__ __launch_bounds__(256) void fused_kernel(
    const float* __restrict__ lfeats, const float* __restrict__ rfeats,
    const int* __restrict__ lstart, const int* __restrict__ rstart,
    const float* __restrict__ W1, const float* __restrict__ b1,
    const float* __restrict__ Wc1, const float* __restrict__ bc1,
    const float* __restrict__ Wc2, const float* __restrict__ bc2,
    float* __restrict__ out, int nunits)
{
    const int lane = threadIdx.x & 63;
    const int wv   = threadIdx.x >> 6;
    const int row  = blockIdx.x * 4 + wv;     // one batch row per wave
    const int r    = lane & 31;   // A row / B col within tile
    const int hh   = lane >> 5;   // k-half: 0 -> k0..7, 1 -> k8..15
    const int nmax = nunits - 1;
    const int ofs1 = hh ? 5 : 4;  // x1 window: f4..7 (hh=0) / f5..8 (hh=1)

    // ---- LDS ----
    __shared__ __align__(16) short sBh[2][32][16];
    __shared__ __align__(16) short sBl[2][32][16];
    __shared__ __align__(16) float rowbuf[4][128];

    // ---- stage B fragments (W1 cols + bias row at k=9, hi/lo) ----
    {
        const int t    = threadIdx.x;
        const int tile = t >> 7;
        const int col  = (t >> 2) & 31;
        const int k0   = (t & 3) * 4;
        const int ch   = tile * 32 + col;
#pragma unroll
        for (int q = 0; q < 4; ++q) {
            const int k = k0 + q;
            float v = 0.0f;
            if (k < 9) v = W1[k * 64 + ch];
            else if (k == 9) v = b1[ch];
            unsigned hi = rlo_f(v);
            float d = v - __uint_as_float(hi << 16);
            sBh[tile][col][k] = (short)hi;
            sBl[tile][col][k] = (short)rlo_f(d);
        }
    }
    __syncthreads();

    const s16x8 bh0 = *reinterpret_cast<const s16x8*>(&sBh[0][r][hh * 8]);
    const s16x8 bh1 = *reinterpret_cast<const s16x8*>(&sBh[1][r][hh * 8]);
    const s16x8 bl0 = *reinterpret_cast<const s16x8*>(&sBl[0][r][hh * 8]);
    const s16x8 bl1 = *reinterpret_cast<const s16x8*>(&sBl[1][r][hh * 8]);

    // persistent zero accumulator seed (MFMA D != C)
    const f32x16 kZ = (f32x16)0.0f;

    // ---- segment boundaries for this row, both sides ----
    const int bidx = row + (lane <= 1 ? lane : 1);
    const int svl = lstart[bidx];
    const int svr = rstart[bidx];
    const int sLv = __shfl(svl, 0, 64);
    const int eL  = __shfl(svl, 1, 64);
    const int sRv = __shfl(svr, 0, 64);
    const int eR  = __shfl(svr, 1, 64);

#define FETCH_(F, POS, Q0,Q1,Q2,Q3,Q4,Q5,Q6,Q7) do {                      \
        int u_ = (POS) + r; if (u_ > nmax) u_ = nmax;                     \
        const float* fp_ = (F) + (size_t)u_ * 9;                          \
        f32x4 x0_ = *reinterpret_cast<const f32x4_u*>(fp_);               \
        f32x4 x1_ = *reinterpret_cast<const f32x4_u*>(fp_ + ofs1);        \
        Q0 = hh ? x1_.w : x0_.x;                                          \
        Q1 = x0_.y; Q2 = x0_.z; Q3 = x0_.w;                               \
        Q4 = x1_.x; Q5 = x1_.y; Q6 = x1_.z; Q7 = x1_.w;                   \
    } while (0)

#define CONV_(Q0,Q1,Q2,Q3,Q4,Q5,Q6,Q7, CNT, AH, AL) do {                  \
    unsigned u0_=__float_as_uint(Q0), u1_=__float_as_uint(Q1),            \
             u2_=__float_as_uint(Q2), u3_=__float_as_uint(Q3),            \
             u4_=__float_as_uint(Q4), u5_=__float_as_uint(Q5),            \
             u6_=__float_as_uint(Q6), u7_=__float_as_uint(Q7);            \
    float d0_=Q0-__uint_as_float(u0_&0xffff0000u);                        \
    float d1_=Q1-__uint_as_float(u1_&0xffff0000u);                        \
    float d2_=Q2-__uint_as_float(u2_&0xffff0000u);                        \
    float d3_=Q3-__uint_as_float(u3_&0xffff0000u);                        \
    float d4_=Q4-__uint_as_float(u4_&0xffff0000u);                        \
    float d5_=Q5-__uint_as_float(u5_&0xffff0000u);                        \
    float d6_=Q6-__uint_as_float(u6_&0xffff0000u);                        \
    float d7_=Q7-__uint_as_float(u7_&0xffff0000u);                        \
    unsigned h01_=(u0_>>16)|(hh?0x3F800000u:(u1_&0xffff0000u));           \
    unsigned l01_=rlo_f(d0_)|(hh?0u:rhi_f(d1_));                          \
    unsigned h23_=(u2_>>16)|(u3_&0xffff0000u);                            \
    unsigned h45_=(u4_>>16)|(u5_&0xffff0000u);                            \
    unsigned h67_=(u6_>>16)|(u7_&0xffff0000u);                            \
    unsigned l23_=rlo_f(d2_)|rhi_f(d3_);                                  \
    unsigned l45_=rlo_f(d4_)|rhi_f(d5_);                                  \
    unsigned l67_=rlo_f(d6_)|rhi_f(d7_);                                  \
    const bool v_ = (r < (CNT));                                          \
    const bool k_ = v_ && (hh == 0);                                      \
    AH.u[0]=v_?h01_:0u; AL.u[0]=v_?l01_:0u;                               \
    AH.u[1]=k_?h23_:0u; AL.u[1]=k_?l23_:0u;                               \
    AH.u[2]=k_?h45_:0u; AL.u[2]=k_?l45_:0u;                               \
    AH.u[3]=k_?h67_:0u; AL.u[3]=k_?l67_:0u;                               \
} while (0)

#define MFMAEPI_(AH, AL, A0, A1) do {                                     \
    f32x16 c0_ = __builtin_amdgcn_mfma_f32_32x32x16_bf16(AL.v, bh0, kZ, 0,0,0); \
    c0_ = __builtin_amdgcn_mfma_f32_32x32x16_bf16(AH.v, bl0, c0_, 0,0,0); \
    c0_ = __builtin_amdgcn_mfma_f32_32x32x16_bf16(AH.v, bh0, c0_, 0,0,0); \
    f32x16 c1_ = __builtin_amdgcn_mfma_f32_32x32x16_bf16(AL.v, bh1, kZ, 0,0,0); \
    c1_ = __builtin_amdgcn_mfma_f32_32x32x16_bf16(AH.v, bl1, c1_, 0,0,0); \
    c1_ = __builtin_amdgcn_mfma_f32_32x32x16_bf16(AH.v, bh1, c1_, 0,0,0); \
    float sA_=0.f,sB_=0.f,sC_=0.f,sD_=0.f,tA_=0.f,tB_=0.f,tC_=0.f,tD_=0.f;\
    _Pragma("unroll")                                                     \
    for (int t_=0; t_<4; ++t_) {                                          \
        sA_+=fmaxf(c0_[t_],0.f);    sB_+=fmaxf(c0_[t_+4],0.f);            \
        sC_+=fmaxf(c0_[t_+8],0.f);  sD_+=fmaxf(c0_[t_+12],0.f);           \
        tA_+=fmaxf(c1_[t_],0.f);    tB_+=fmaxf(c1_[t_+4],0.f);            \
        tC_+=fmaxf(c1_[t_+8],0.f);  tD_+=fmaxf(c1_[t_+12],0.f);           \
    }                                                                     \
    A0 += (sA_+sB_)+(sC_+sD_);                                            \
    A1 += (tA_+tB_)+(tC_+tD_);                                            \
} while (0)

#define STEP_(S) do {                                                     \
    int cnt_ = e##S - base##S; if (cnt_ > 32) cnt_ = 32;                  \
    abfrag_t AH_, AL_;                                                    \
    CONV_(p0##S,p1##S,p2##S,p3##S,p4##S,p5##S,p6##S,p7##S, cnt_, AH_, AL_);\
    int nxt_ = base##S + cnt_;                                            \
    int fpos_ = (nxt_ < e##S) ? nxt_ : 0;   /* dummy fetch: L2-resident */ \
    FETCH_(f##S, fpos_, p0##S,p1##S,p2##S,p3##S,p4##S,p5##S,p6##S,p7##S); \
    MFMAEPI_(AH_, AL_, ac0##S, ac1##S);                                   \
    base##S = nxt_;                                                       \
} while (0)

    // ---- per-side stream state (1 segment per side) ----
    const float* __restrict__ fL = lfeats;
    const float* __restrict__ fR = rfeats;
    int baseL = sLv, baseR = sRv;
    float ac0L = 0.f, ac1L = 0.f, ac0R = 0.f, ac1R = 0.f;
    float p0L=0,p1L=0,p2L=0,p3L=0,p4L=0,p5L=0,p6L=0,p7L=0;
    float p0R=0,p1R=0,p2R=0,p3R=0,p4R=0,p5R=0,p6R=0,p7R=0;

    // unconditional clamped initial fetches (independent -> overlapped)
    FETCH_(fL, baseL, p0L,p1L,p2L,p3L,p4L,p5L,p6L,p7L);
    FETCH_(fR, baseR, p0R,p1R,p2R,p3R,p4R,p5R,p6R,p7R);

    bool aL = baseL < eL, aR = baseR < eR;
    while (aL && aR) {           // fused dual-stream body
        STEP_(L);
        STEP_(R);
        aL = baseL < eL; aR = baseR < eR;
    }
    while (aL) { STEP_(L); aL = baseL < eL; }
    while (aR) { STEP_(R); aR = baseR < eR; }

    // ---- single unconditional flush per side ----
    ac0L += __shfl_xor(ac0L, 32, 64);
    ac1L += __shfl_xor(ac1L, 32, 64);
    rowbuf[wv][lane]      = hh ? ac1L : ac0L;   // left channels 0..63
    ac0R += __shfl_xor(ac0R, 32, 64);
    ac1R += __shfl_xor(ac1R, 32, 64);
    rowbuf[wv][64 + lane] = hh ? ac1R : ac0R;   // right channels 0..63

#undef STEP_
#undef MFMAEPI_
#undef CONV_
#undef FETCH_

    // drain rowbuf ds_writes (same-wave RAW; no cross-wave sharing)
    asm volatile("s_waitcnt lgkmcnt(0)" ::: "memory");

    // ================= HEAD: 1 row per wave, split across half-waves ========
    // hh half-wave dots features [hh*64, hh*64+64); shfl_xor(32) combines
    // halves BEFORE relu; then reduce over hidden units j and store.
    {
        const int j = lane & 31;
        const float* __restrict__ rb = &rowbuf[wv][hh * 64];
        const float* __restrict__ wc = Wc1 + (hh * 64) * 32 + j;  // coalesced col

        float accA = hh ? 0.0f : bc1[j], accB = 0.0f;
#pragma unroll 8
        for (int k = 0; k < 64; k += 4) {
            f32x4 v = *reinterpret_cast<const f32x4*>(rb + k);
            accA = fmaf(v.x, wc[(k + 0) * 32], accA);
            accB = fmaf(v.y, wc[(k + 1) * 32], accB);
            accA = fmaf(v.z, wc[(k + 2) * 32], accA);
            accB = fmaf(v.w, wc[(k + 3) * 32], accB);
        }
        float hsv = accA + accB;
        hsv += __shfl_xor(hsv, 32, 64);            // combine k-halves (pre-relu)
        float h = fmaxf(hsv, 0.0f) * Wc2[j];
#pragma unroll
        for (int off = 16; off > 0; off >>= 1) h += __shfl_xor(h, off, 64);

        if (lane == 0) {
            float logit = h + bc2[0];
            out[row] = 1.0f / (1.0f + expf(-logit));
        }
    }
}

// ---------------------------------------------------------------------------
extern "C" void kernel_launch(void* const* d_in, const int* in_sizes, int n_in,
                              void* d_out, int out_size, void* d_ws, size_t ws_size,
                              hipStream_t stream)
{
    const float* lfeats = (const float*)d_in[0];
    const float* rfeats = (const float*)d_in[1];
    const int*   lseg   = (const int*)d_in[2];
    const int*   rseg   = (const int*)d_in[3];
    const float* W1     = (const float*)d_in[4];
    const float* b1     = (const float*)d_in[5];
    const float* Wc1    = (const float*)d_in[6];
    const float* bc1    = (const float*)d_in[7];
    const float* Wc2    = (const float*)d_in[8];
    const float* bc2    = (const float*)d_in[9];
    float* out = (float*)d_out;

    const int n = in_sizes[2];  // N_UNITS per side

    int* lstart = (int*)d_ws;
    int* rstart = lstart + (BATCH_C + 16);

    seg_starts_kernel<<<dim3((n + 255) / 256, 2), 256, 0, stream>>>(
        lseg, rseg, n, lstart, rstart);

    fused_kernel<<<BATCH_C / 4, 256, 0, stream>>>(
        lfeats, rfeats, lstart, rstart, W1, b1, Wc1, bc1, Wc2, bc2, out, n);
}

// Round 16
// 36.376 us; speedup vs baseline: 12.5916x; 1.2391x over previous
//
#include <hip/hip_runtime.h>
#include <math.h>

#define BATCH_C 16384
#define SPW 2   // segments (batch rows) per wave; each wave does both sides + head

typedef float f32x4  __attribute__((ext_vector_type(4)));
typedef f32x4 __attribute__((aligned(4))) f32x4_u;   // dword-aligned vector load
typedef float f32x16 __attribute__((ext_vector_type(16)));
typedef short s16x8  __attribute__((ext_vector_type(8)));

typedef union { unsigned u[4]; s16x8 v; } abfrag_t;

// branchless RNE fp32->bf16 (no NaN inputs here), result in LOW 16 bits
static __device__ inline unsigned rlo_f(float x) {
    unsigned u = __float_as_uint(x);
    return (u + 0x7fffu + ((u >> 16) & 1u)) >> 16;
}
// same, result pre-positioned in HIGH 16 bits
static __device__ inline unsigned rhi_f(float x) {
    unsigned u = __float_as_uint(x);
    return (u + 0x7fffu + ((u >> 16) & 1u)) & 0xffff0000u;
}

// ---------------------------------------------------------------------------
// Kernel 1: segment boundary detection for BOTH sides (grid.y = side).
// start[b] = first index i with seg[i] >= b; start[BATCH]=n.
// ---------------------------------------------------------------------------
__global__ __launch_bounds__(256) void seg_starts_kernel(
    const int* __restrict__ lseg, const int* __restrict__ rseg, int n,
    int* __restrict__ lstart, int* __restrict__ rstart)
{
    const int* __restrict__ seg = blockIdx.y ? rseg : lseg;
    int* __restrict__ start = blockIdx.y ? rstart : lstart;
    int i = blockIdx.x * blockDim.x + threadIdx.x;
    if (i >= n) return;
    int s = seg[i];
    int prev = (i == 0) ? -1 : seg[i - 1];
    for (int b = prev + 1; b <= s; ++b) start[b] = i;
    if (i == n - 1) {
        for (int b = s + 1; b <= BATCH_C; ++b) start[b] = n;
    }
}

// ---------------------------------------------------------------------------
// Kernel 2 (FUSED): per-unit MLP (9->64, ReLU) + ragged segment sum via MFMA
// for BOTH sides processed as two CONCURRENT streams in one loop body
// (single basic block -> scheduler interleaves the 4 independent MFMA
// chains and the two conversion blocks), then the head MLP for the wave's
// own 2 rows. bf16 3-term split keeps fp32-level accuracy (absmax ~1e-4).
// launch_bounds(256,2): accumulators stay in VGPRs (no AGPR move tax).
// Persistent kZ zero vector seeds each MFMA chain (D != C) - no per-window
// accumulator zero-init. Branchless FETCH + branchless dummy prefetch
// (clamped to unit 0, L2-resident) keep the body branch-free except the
// rare per-segment flush.
//
// SESSION FINAL (R16 = exact revert to the measured-best R9 build, 36.45us).
// Evidence for stopping here: R14 ablation (CONV/FETCH/MFMA/EPI removals all
// flat within 6%) shows the remaining time is a structural latency/overhead
// floor, and all seven structural variants tried (R5-R15) measured >= this.
// ---------------------------------------------------------------------------
__global__ __launch_bounds__(256, 2) void fused_kernel(
    const float* __restrict__ lfeats, const float* __restrict__ rfeats,
    const int* __restrict__ lstart, const int* __restrict__ rstart,
    const float* __restrict__ W1, const float* __restrict__ b1,
    const float* __restrict__ Wc1, const float* __restrict__ bc1,
    const float* __restrict__ Wc2, const float* __restrict__ bc2,
    float* __restrict__ out, int nunits)
{
    const int lane = threadIdx.x & 63;
    const int wv   = threadIdx.x >> 6;
    const int S0   = (blockIdx.x * 4 + wv) * SPW;
    const int r    = lane & 31;   // A row / B col within tile
    const int hh   = lane >> 5;   // k-half: 0 -> k0..7, 1 -> k8..15
    const int nmax = nunits - 1;
    const int ofs1 = hh ? 5 : 4;  // x1 window: f4..7 (hh=0) / f5..8 (hh=1)

    // ---- LDS ----
    __shared__ __align__(16) short sBh[2][32][16];
    __shared__ __align__(16) short sBl[2][32][16];
    __shared__ __align__(16) float sWT[32 * 132];   // Wc1 transposed, pad 132
    __shared__ float sb2[32];
    __shared__ float sw2v[32];
    __shared__ __align__(16) float rowbuf[4][SPW][128];

    // ---- stage B fragments (W1 cols + bias row at k=9, hi/lo) ----
    {
        const int t    = threadIdx.x;
        const int tile = t >> 7;
        const int col  = (t >> 2) & 31;
        const int k0   = (t & 3) * 4;
        const int ch   = tile * 32 + col;
#pragma unroll
        for (int q = 0; q < 4; ++q) {
            const int k = k0 + q;
            float v = 0.0f;
            if (k < 9) v = W1[k * 64 + ch];
            else if (k == 9) v = b1[ch];
            unsigned hi = rlo_f(v);
            float d = v - __uint_as_float(hi << 16);
            sBh[tile][col][k] = (short)hi;
            sBl[tile][col][k] = (short)rlo_f(d);
        }
    }
    // ---- stage Wc1 transposed + head vectors ----
    for (int idx = threadIdx.x; idx < 128 * 32; idx += 256) {
        sWT[(idx & 31) * 132 + (idx >> 5)] = Wc1[idx];
    }
    if (threadIdx.x < 32) {
        sb2[threadIdx.x]  = bc1[threadIdx.x];
        sw2v[threadIdx.x] = Wc2[threadIdx.x];
    }
    __syncthreads();

    const s16x8 bh0 = *reinterpret_cast<const s16x8*>(&sBh[0][r][hh * 8]);
    const s16x8 bh1 = *reinterpret_cast<const s16x8*>(&sBh[1][r][hh * 8]);
    const s16x8 bl0 = *reinterpret_cast<const s16x8*>(&sBl[0][r][hh * 8]);
    const s16x8 bl1 = *reinterpret_cast<const s16x8*>(&sBl[1][r][hh * 8]);

    // persistent zero accumulator seed (MFMA D != C)
    const f32x16 kZ = (f32x16)0.0f;

    // ---- pre-zero this wave's rowbuf (covers empty segments) ----
    rowbuf[wv][0][lane] = 0.0f;  rowbuf[wv][0][64 + lane] = 0.0f;
    rowbuf[wv][1][lane] = 0.0f;  rowbuf[wv][1][64 + lane] = 0.0f;

    // ---- segment boundaries for both sides ----
    const int bidx = S0 + (lane <= SPW ? lane : SPW);
    const int svl = lstart[bidx];
    const int svr = rstart[bidx];
    const int sLv = __shfl(svl, 0, 64);
    const int e1L = __shfl(svl, 1, 64);
    const int e2L = __shfl(svl, 2, 64);
    const int sRv = __shfl(svr, 0, 64);
    const int e1R = __shfl(svr, 1, 64);
    const int e2R = __shfl(svr, 2, 64);
    const int endL = e2L, endR = e2R;

#define FETCH_(F, POS, Q0,Q1,Q2,Q3,Q4,Q5,Q6,Q7) do {                      \
        int u_ = (POS) + r; if (u_ > nmax) u_ = nmax;                     \
        const float* fp_ = (F) + (size_t)u_ * 9;                          \
        f32x4 x0_ = *reinterpret_cast<const f32x4_u*>(fp_);               \
        f32x4 x1_ = *reinterpret_cast<const f32x4_u*>(fp_ + ofs1);        \
        Q0 = hh ? x1_.w : x0_.x;                                          \
        Q1 = x0_.y; Q2 = x0_.z; Q3 = x0_.w;                               \
        Q4 = x1_.x; Q5 = x1_.y; Q6 = x1_.z; Q7 = x1_.w;                   \
    } while (0)

#define CONV_(Q0,Q1,Q2,Q3,Q4,Q5,Q6,Q7, CNT, AH, AL) do {                  \
    unsigned u0_=__float_as_uint(Q0), u1_=__float_as_uint(Q1),            \
             u2_=__float_as_uint(Q2), u3_=__float_as_uint(Q3),            \
             u4_=__float_as_uint(Q4), u5_=__float_as_uint(Q5),            \
             u6_=__float_as_uint(Q6), u7_=__float_as_uint(Q7);            \
    float d0_=Q0-__uint_as_float(u0_&0xffff0000u);                        \
    float d1_=Q1-__uint_as_float(u1_&0xffff0000u);                        \
    float d2_=Q2-__uint_as_float(u2_&0xffff0000u);                        \
    float d3_=Q3-__uint_as_float(u3_&0xffff0000u);                        \
    float d4_=Q4-__uint_as_float(u4_&0xffff0000u);                        \
    float d5_=Q5-__uint_as_float(u5_&0xffff0000u);                        \
    float d6_=Q6-__uint_as_float(u6_&0xffff0000u);                        \
    float d7_=Q7-__uint_as_float(u7_&0xffff0000u);                        \
    unsigned h01_=(u0_>>16)|(hh?0x3F800000u:(u1_&0xffff0000u));           \
    unsigned l01_=rlo_f(d0_)|(hh?0u:rhi_f(d1_));                          \
    unsigned h23_=(u2_>>16)|(u3_&0xffff0000u);                            \
    unsigned h45_=(u4_>>16)|(u5_&0xffff0000u);                            \
    unsigned h67_=(u6_>>16)|(u7_&0xffff0000u);                            \
    unsigned l23_=rlo_f(d2_)|rhi_f(d3_);                                  \
    unsigned l45_=rlo_f(d4_)|rhi_f(d5_);                                  \
    unsigned l67_=rlo_f(d6_)|rhi_f(d7_);                                  \
    const bool v_ = (r < (CNT));                                          \
    const bool k_ = v_ && (hh == 0);                                      \
    AH.u[0]=v_?h01_:0u; AL.u[0]=v_?l01_:0u;                               \
    AH.u[1]=k_?h23_:0u; AL.u[1]=k_?l23_:0u;                               \
    AH.u[2]=k_?h45_:0u; AL.u[2]=k_?l45_:0u;                               \
    AH.u[3]=k_?h67_:0u; AL.u[3]=k_?l67_:0u;                               \
} while (0)

#define MFMAEPI_(AH, AL, A0, A1) do {                                     \
    f32x16 c0_ = __builtin_amdgcn_mfma_f32_32x32x16_bf16(AL.v, bh0, kZ, 0,0,0); \
    c0_ = __builtin_amdgcn_mfma_f32_32x32x16_bf16(AH.v, bl0, c0_, 0,0,0); \
    c0_ = __builtin_amdgcn_mfma_f32_32x32x16_bf16(AH.v, bh0, c0_, 0,0,0); \
    f32x16 c1_ = __builtin_amdgcn_mfma_f32_32x32x16_bf16(AL.v, bh1, kZ, 0,0,0); \
    c1_ = __builtin_amdgcn_mfma_f32_32x32x16_bf16(AH.v, bl1, c1_, 0,0,0); \
    c1_ = __builtin_amdgcn_mfma_f32_32x32x16_bf16(AH.v, bh1, c1_, 0,0,0); \
    float sA_=0.f,sB_=0.f,sC_=0.f,sD_=0.f,tA_=0.f,tB_=0.f,tC_=0.f,tD_=0.f;\
    _Pragma("unroll")                                                     \
    for (int t_=0; t_<4; ++t_) {                                          \
        sA_+=fmaxf(c0_[t_],0.f);    sB_+=fmaxf(c0_[t_+4],0.f);            \
        sC_+=fmaxf(c0_[t_+8],0.f);  sD_+=fmaxf(c0_[t_+12],0.f);           \
        tA_+=fmaxf(c1_[t_],0.f);    tB_+=fmaxf(c1_[t_+4],0.f);            \
        tC_+=fmaxf(c1_[t_+8],0.f);  tD_+=fmaxf(c1_[t_+12],0.f);           \
    }                                                                     \
    A0 += (sA_+sB_)+(sC_+sD_);                                            \
    A1 += (tA_+tB_)+(tC_+tD_);                                            \
} while (0)

#define STEP_(S) do {                                                     \
    int cnt_ = ec##S - base##S; if (cnt_ > 32) cnt_ = 32;                 \
    abfrag_t AH_, AL_;                                                    \
    CONV_(p0##S,p1##S,p2##S,p3##S,p4##S,p5##S,p6##S,p7##S, cnt_, AH_, AL_);\
    int nxt_ = base##S + cnt_;                                            \
    int fpos_ = (nxt_ < end##S) ? nxt_ : 0;  /* dummy fetch: L2-resident */\
    FETCH_(f##S, fpos_, p0##S,p1##S,p2##S,p3##S,p4##S,p5##S,p6##S,p7##S); \
    MFMAEPI_(AH_, AL_, ac0##S, ac1##S);                                   \
    base##S = nxt_;                                                       \
} while (0)

#define FLUSH_(S, SIDEOFS) do {                                           \
    if (base##S >= ec##S) {                                               \
        ac0##S += __shfl_xor(ac0##S, 32, 64);                             \
        ac1##S += __shfl_xor(ac1##S, 32, 64);                             \
        if (cs##S < SPW)                                                  \
            rowbuf[wv][cs##S][(SIDEOFS) + lane] = hh ? ac1##S : ac0##S;   \
        ac0##S = 0.0f; ac1##S = 0.0f;                                     \
        ++cs##S; ec##S = e2##S;                                           \
    }                                                                     \
} while (0)

    // ---- per-side stream state ----
    const float* __restrict__ fL = lfeats;
    const float* __restrict__ fR = rfeats;
    int baseL = sLv, baseR = sRv;
    int csL, ecL, csR, ecR;
    if (baseL >= e1L) { csL = 1; ecL = e2L; } else { csL = 0; ecL = e1L; }
    if (baseR >= e1R) { csR = 1; ecR = e2R; } else { csR = 0; ecR = e1R; }
    float ac0L = 0.f, ac1L = 0.f, ac0R = 0.f, ac1R = 0.f;
    float p0L=0,p1L=0,p2L=0,p3L=0,p4L=0,p5L=0,p6L=0,p7L=0;
    float p0R=0,p1R=0,p2R=0,p3R=0,p4R=0,p5R=0,p6R=0,p7R=0;

    if (baseL < endL) FETCH_(fL, baseL, p0L,p1L,p2L,p3L,p4L,p5L,p6L,p7L);
    if (baseR < endR) FETCH_(fR, baseR, p0R,p1R,p2R,p3R,p4R,p5R,p6R,p7R);

    bool aL = baseL < endL, aR = baseR < endR;
    while (aL && aR) {           // fused dual-stream body: one big BB
        STEP_(L);
        STEP_(R);
        FLUSH_(L, 0);
        FLUSH_(R, 64);
        aL = baseL < endL; aR = baseR < endR;
    }
    while (aL) { STEP_(L); FLUSH_(L, 0);  aL = baseL < endL; }
    while (aR) { STEP_(R); FLUSH_(R, 64); aR = baseR < endR; }

#undef FLUSH_
#undef STEP_
#undef MFMAEPI_
#undef CONV_
#undef FETCH_

    // drain rowbuf ds_writes (same-wave RAW; no cross-wave sharing)
    asm volatile("s_waitcnt lgkmcnt(0)" ::: "memory");

    // ================= HEAD: 2 rows per wave (half-wave each) =================
    {
        const int j = lane & 31;          // hidden unit
        const float* __restrict__ rb = &rowbuf[wv][hh][0];   // row = S0 + hh
        const float* __restrict__ wt = &sWT[j * 132];

        float accA = sb2[j], accB = 0.0f;
#pragma unroll 8
        for (int q = 0; q < 32; ++q) {
            f32x4 v = *reinterpret_cast<const f32x4*>(rb + q * 4);
            f32x4 w = *reinterpret_cast<const f32x4*>(wt + q * 4);
            accA = fmaf(v.x, w.x, accA);
            accB = fmaf(v.y, w.y, accB);
            accA = fmaf(v.z, w.z, accA);
            accB = fmaf(v.w, w.w, accB);
        }
        float hsv = fmaxf(accA + accB, 0.0f) * sw2v[j];
#pragma unroll
        for (int off = 16; off > 0; off >>= 1) hsv += __shfl_xor(hsv, off, 64);

        if (j == 0) {
            float logit = hsv + bc2[0];
            out[S0 + hh] = 1.0f / (1.0f + expf(-logit));
        }
    }
}

// ---------------------------------------------------------------------------
extern "C" void kernel_launch(void* const* d_in, const int* in_sizes, int n_in,
                              void* d_out, int out_size, void* d_ws, size_t ws_size,
                              hipStream_t stream)
{
    const float* lfeats = (const float*)d_in[0];
    const float* rfeats = (const float*)d_in[1];
    const int*   lseg   = (const int*)d_in[2];
    const int*   rseg   = (const int*)d_in[3];
    const float* W1     = (const float*)d_in[4];
    const float* b1     = (const float*)d_in[5];
    const float* Wc1    = (const float*)d_in[6];
    const float* bc1    = (const float*)d_in[7];
    const float* Wc2    = (const float*)d_in[8];
    const float* bc2    = (const float*)d_in[9];
    float* out = (float*)d_out;

    const int n = in_sizes[2];  // N_UNITS per side

    int* lstart = (int*)d_ws;
    int* rstart = lstart + (BATCH_C + 16);

    seg_starts_kernel<<<dim3((n + 255) / 256, 2), 256, 0, stream>>>(
        lseg, rseg, n, lstart, rstart);

    fused_kernel<<<BATCH_C / (SPW * 4), 256, 0, stream>>>(
        lfeats, rfeats, lstart, rstart, W1, b1, Wc1, bc1, Wc2, bc2, out, n);
}